// Round 1
// baseline (1322.238 us; speedup 1.0000x reference)
//
#include <hip/hip_runtime.h>
#include <hip/hip_bf16.h>

#define NN 50000
#define EE 1600000
#define DIN 128
#define HH 256
#define DOUT 128

// ---------------- CSR build ----------------

__global__ __launch_bounds__(256) void hist_kernel(const int* __restrict__ dst, int* __restrict__ deg, int E) {
    int e = blockIdx.x * 256 + threadIdx.x;
    if (e < E) atomicAdd(&deg[dst[e]], 1);
}

#define SCAN_B 256

__global__ __launch_bounds__(SCAN_B) void scan1_kernel(const int* __restrict__ deg, int* __restrict__ exc,
                                                       int* __restrict__ bsum, int n) {
    __shared__ int tmp[SCAN_B];
    int i = blockIdx.x * SCAN_B + threadIdx.x;
    int v = (i < n) ? deg[i] : 0;
    tmp[threadIdx.x] = v;
    __syncthreads();
    for (int o = 1; o < SCAN_B; o <<= 1) {
        int t = (threadIdx.x >= o) ? tmp[threadIdx.x - o] : 0;
        __syncthreads();
        tmp[threadIdx.x] += t;
        __syncthreads();
    }
    if (i < n) exc[i] = tmp[threadIdx.x] - v;  // exclusive within block
    if (threadIdx.x == SCAN_B - 1) bsum[blockIdx.x] = tmp[SCAN_B - 1];
}

__global__ __launch_bounds__(SCAN_B) void scan2_kernel(int* __restrict__ bsum, int nb) {
    __shared__ int tmp[SCAN_B];
    int v = (threadIdx.x < nb) ? bsum[threadIdx.x] : 0;
    tmp[threadIdx.x] = v;
    __syncthreads();
    for (int o = 1; o < SCAN_B; o <<= 1) {
        int t = (threadIdx.x >= o) ? tmp[threadIdx.x - o] : 0;
        __syncthreads();
        tmp[threadIdx.x] += t;
        __syncthreads();
    }
    if (threadIdx.x < nb) bsum[threadIdx.x] = tmp[threadIdx.x] - v;  // exclusive block offsets
}

__global__ __launch_bounds__(SCAN_B) void scan3_kernel(int* __restrict__ exc, const int* __restrict__ bsum,
                                                       int* __restrict__ cursor, int n, int E) {
    int i = blockIdx.x * SCAN_B + threadIdx.x;
    if (i < n) {
        int v = exc[i] + bsum[blockIdx.x];
        exc[i] = v;
        cursor[i] = v;
    }
    if (i == n) exc[n] = E;
}

__global__ __launch_bounds__(256) void scatter_kernel(const int* __restrict__ src, const int* __restrict__ dst,
                                                      int* __restrict__ cursor, int* __restrict__ es, int E) {
    int e = blockIdx.x * 256 + threadIdx.x;
    if (e < E) {
        int d = dst[e];
        int pos = atomicAdd(&cursor[d], 1);
        es[pos] = src[e];
    }
}

// ---------------- fp32 GEMM: H = X @ W  (X:[n,K] row-major, W:[K,Cout] row-major) ----------------

__global__ __launch_bounds__(256) void gemm_kernel(const float* __restrict__ X, const float* __restrict__ W,
                                                   float* __restrict__ Hout, int n, int K, int Cout) {
    const int BM = 64, BN = 64, BK = 16;
    __shared__ float As[BK][BM + 1];  // As[k][m]
    __shared__ float Bs[BK][BN];      // Bs[k][c]
    int tid = threadIdx.x;
    int row0 = blockIdx.y * BM;
    int col0 = blockIdx.x * BN;
    int tx = tid % 16, ty = tid / 16;

    float acc[4][4];
#pragma unroll
    for (int i = 0; i < 4; ++i)
#pragma unroll
        for (int j = 0; j < 4; ++j) acc[i][j] = 0.f;

    int lm = tid / 4;          // 0..63 (row within A tile)
    int lk4 = (tid % 4) * 4;   // 0,4,8,12 (k within A tile)
    int lk = tid / 16;         // 0..15 (k within B tile)
    int ln4 = (tid % 16) * 4;  // col within B tile

    for (int k0 = 0; k0 < K; k0 += BK) {
        float4 av = make_float4(0.f, 0.f, 0.f, 0.f);
        int gr = row0 + lm;
        if (gr < n) av = *(const float4*)(X + (size_t)gr * K + k0 + lk4);
        As[lk4 + 0][lm] = av.x;
        As[lk4 + 1][lm] = av.y;
        As[lk4 + 2][lm] = av.z;
        As[lk4 + 3][lm] = av.w;
        float4 bv = *(const float4*)(W + (size_t)(k0 + lk) * Cout + col0 + ln4);
        *(float4*)&Bs[lk][ln4] = bv;
        __syncthreads();
#pragma unroll
        for (int k = 0; k < BK; ++k) {
            float a0 = As[k][ty * 4 + 0], a1 = As[k][ty * 4 + 1];
            float a2 = As[k][ty * 4 + 2], a3 = As[k][ty * 4 + 3];
            float b0 = Bs[k][tx * 4 + 0], b1 = Bs[k][tx * 4 + 1];
            float b2 = Bs[k][tx * 4 + 2], b3 = Bs[k][tx * 4 + 3];
            acc[0][0] = fmaf(a0, b0, acc[0][0]); acc[0][1] = fmaf(a0, b1, acc[0][1]);
            acc[0][2] = fmaf(a0, b2, acc[0][2]); acc[0][3] = fmaf(a0, b3, acc[0][3]);
            acc[1][0] = fmaf(a1, b0, acc[1][0]); acc[1][1] = fmaf(a1, b1, acc[1][1]);
            acc[1][2] = fmaf(a1, b2, acc[1][2]); acc[1][3] = fmaf(a1, b3, acc[1][3]);
            acc[2][0] = fmaf(a2, b0, acc[2][0]); acc[2][1] = fmaf(a2, b1, acc[2][1]);
            acc[2][2] = fmaf(a2, b2, acc[2][2]); acc[2][3] = fmaf(a2, b3, acc[2][3]);
            acc[3][0] = fmaf(a3, b0, acc[3][0]); acc[3][1] = fmaf(a3, b1, acc[3][1]);
            acc[3][2] = fmaf(a3, b2, acc[3][2]); acc[3][3] = fmaf(a3, b3, acc[3][3]);
        }
        __syncthreads();
    }
#pragma unroll
    for (int i = 0; i < 4; ++i) {
        int r = row0 + ty * 4 + i;
        if (r < n) {
            float4 o = make_float4(acc[i][0], acc[i][1], acc[i][2], acc[i][3]);
            *(float4*)(Hout + (size_t)r * Cout + col0 + tx * 4) = o;
        }
    }
}

// ---------------- per-node attention logit dots: s1 = H@a1, s2 = H@a2 ----------------

__global__ __launch_bounds__(256) void rowdots_kernel(const float* __restrict__ H, const float* __restrict__ a1,
                                                      const float* __restrict__ a2, float* __restrict__ s1,
                                                      float* __restrict__ s2, int n, int C) {
    int w = (blockIdx.x * 256 + threadIdx.x) >> 6;
    int lane = threadIdx.x & 63;
    if (w >= n) return;
    const float* hp = H + (size_t)w * C;
    float acc1 = 0.f, acc2 = 0.f;
    for (int c = lane; c < C; c += 64) {
        float hv = hp[c];
        acc1 = fmaf(hv, a1[c], acc1);
        acc2 = fmaf(hv, a2[c], acc2);
    }
#pragma unroll
    for (int o = 32; o; o >>= 1) {
        acc1 += __shfl_xor(acc1, o, 64);
        acc2 += __shfl_xor(acc2, o, 64);
    }
    if (lane == 0) {
        s1[w] = acc1;
        s2[w] = acc2;
    }
}

// ---------------- aggregation: segment softmax + weighted gather-sum, one wave per node ----------------

template <int VEC, bool RELU, bool SOFTMAX>
__global__ __launch_bounds__(256) void agg_kernel(const float* __restrict__ H, const float* __restrict__ ssrc,
                                                  const float* __restrict__ sdst, const int* __restrict__ off,
                                                  const int* __restrict__ esrc, const float* __restrict__ bias,
                                                  float* __restrict__ out, int n, int C) {
    int w = (blockIdx.x * 256 + threadIdx.x) >> 6;
    int lane = threadIdx.x & 63;
    if (w >= n) return;
    int beg = off[w], end = off[w + 1];
    float sd = sdst[w];

    // pass A: segment max of leaky_relu logits
    float m = -3e38f;
    for (int base = beg; base < end; base += 64) {
        int e = base + lane;
        if (e < end) {
            float v = ssrc[esrc[e]] + sd;
            v = (v > 0.f) ? v : 0.2f * v;
            m = fmaxf(m, v);
        }
    }
#pragma unroll
    for (int o = 32; o; o >>= 1) m = fmaxf(m, __shfl_xor(m, o, 64));

    // pass B: p = exp(e - m); accumulate p * h[src] (unnormalized) + denom
    float acc[VEC];
#pragma unroll
    for (int v = 0; v < VEC; ++v) acc[v] = 0.f;
    float dl = 0.f;
    for (int base = beg; base < end; base += 64) {
        int e = base + lane;
        int s = 0;
        float p = 0.f;
        if (e < end) {
            s = esrc[e];
            float v = ssrc[s] + sd;
            v = (v > 0.f) ? v : 0.2f * v;
            p = __expf(v - m);
            dl += p;
        }
        int rem = end - base;
        int cnt = (rem < 64) ? rem : 64;
        for (int j = 0; j < cnt; ++j) {
            float pj = __shfl(p, j, 64);
            int sj = __shfl(s, j, 64);
            const float* hp = H + (size_t)sj * C + lane * VEC;
            if (VEC == 4) {
                float4 hv = *(const float4*)hp;
                acc[0] = fmaf(pj, hv.x, acc[0]);
                acc[1] = fmaf(pj, hv.y, acc[1]);
                acc[2] = fmaf(pj, hv.z, acc[2]);
                acc[3] = fmaf(pj, hv.w, acc[3]);
            } else {
                float2 hv = *(const float2*)hp;
                acc[0] = fmaf(pj, hv.x, acc[0]);
                acc[1] = fmaf(pj, hv.y, acc[1]);
            }
        }
    }
#pragma unroll
    for (int o = 32; o; o >>= 1) dl += __shfl_xor(dl, o, 64);
    float inv = (dl > 0.f) ? 1.f / dl : 0.f;

    float ov[VEC];
#pragma unroll
    for (int v = 0; v < VEC; ++v) {
        ov[v] = fmaf(acc[v], inv, bias[lane * VEC + v]);
        if (RELU) ov[v] = fmaxf(ov[v], 0.f);
    }
    if (SOFTMAX) {
        float mm = ov[0];
#pragma unroll
        for (int v = 1; v < VEC; ++v) mm = fmaxf(mm, ov[v]);
#pragma unroll
        for (int o = 32; o; o >>= 1) mm = fmaxf(mm, __shfl_xor(mm, o, 64));
        float ssum = 0.f;
#pragma unroll
        for (int v = 0; v < VEC; ++v) {
            ov[v] = __expf(ov[v] - mm);
            ssum += ov[v];
        }
#pragma unroll
        for (int o = 32; o; o >>= 1) ssum += __shfl_xor(ssum, o, 64);
        float si = 1.f / ssum;
#pragma unroll
        for (int v = 0; v < VEC; ++v) ov[v] *= si;
    }
    float* op = out + (size_t)w * C + lane * VEC;
    if (VEC == 4)
        *(float4*)op = make_float4(ov[0], ov[1], ov[2], ov[3]);
    else
        *(float2*)op = make_float2(ov[0], ov[1]);
}

// ---------------- launch ----------------

extern "C" void kernel_launch(void* const* d_in, const int* in_sizes, int n_in,
                              void* d_out, int out_size, void* d_ws, size_t ws_size,
                              hipStream_t stream) {
    const float* x = (const float*)d_in[0];
    const int* ei = (const int*)d_in[1];
    const float* W1 = (const float*)d_in[2];
    const float* a1s = (const float*)d_in[3];
    const float* a1d = (const float*)d_in[4];
    const float* b1 = (const float*)d_in[5];
    const float* W2 = (const float*)d_in[6];
    const float* a2s = (const float*)d_in[7];
    const float* a2d = (const float*)d_in[8];
    const float* b2 = (const float*)d_in[9];
    const float* W3 = (const float*)d_in[10];
    const float* a3s = (const float*)d_in[11];
    const float* a3d = (const float*)d_in[12];
    const float* b3 = (const float*)d_in[13];

    const int n = NN, E = EE;
    const int* src = ei;
    const int* dst = ei + E;

    // workspace layout (256B aligned chunks)
    char* base = (char*)d_ws;
    size_t o = 0;
    auto alloc = [&](size_t bytes) -> char* {
        char* p = base + o;
        o += (bytes + 255) & ~(size_t)255;
        return p;
    };
    int* off = (int*)alloc((n + 1) * sizeof(int));
    int* cur = (int*)alloc((n + 1) * sizeof(int));
    int* bsum = (int*)alloc(1024 * sizeof(int));
    int* es = (int*)alloc((size_t)E * sizeof(int));
    float* ssrc = (float*)alloc((size_t)n * sizeof(float));
    float* sdst = (float*)alloc((size_t)n * sizeof(float));
    float* Hbuf = (float*)alloc((size_t)n * HH * sizeof(float));
    float* Abuf = (float*)alloc((size_t)n * HH * sizeof(float));
    (void)ws_size;

    // --- CSR build (grouped by dst) ---
    hipMemsetAsync(cur, 0, (n + 1) * sizeof(int), stream);
    hist_kernel<<<(E + 255) / 256, 256, 0, stream>>>(dst, cur, E);
    int nb = (n + SCAN_B - 1) / SCAN_B;  // 196
    scan1_kernel<<<nb, SCAN_B, 0, stream>>>(cur, off, bsum, n);
    scan2_kernel<<<1, SCAN_B, 0, stream>>>(bsum, nb);
    scan3_kernel<<<nb, SCAN_B, 0, stream>>>(off, bsum, cur, n, E);
    scatter_kernel<<<(E + 255) / 256, 256, 0, stream>>>(src, dst, cur, es, E);

    int wgrid = (n * 64 + 255) / 256;  // one wave per node

    // --- layer 1: x[N,128] @ W1 -> H[N,256], relu ---
    {
        dim3 g(HH / 64, (n + 63) / 64);
        gemm_kernel<<<g, 256, 0, stream>>>(x, W1, Hbuf, n, DIN, HH);
        rowdots_kernel<<<wgrid, 256, 0, stream>>>(Hbuf, a1s, a1d, ssrc, sdst, n, HH);
        agg_kernel<4, true, false><<<wgrid, 256, 0, stream>>>(Hbuf, ssrc, sdst, off, es, b1, Abuf, n, HH);
    }
    // --- layers 2,3: shared W2 ---
    for (int t = 0; t < 2; ++t) {
        dim3 g(HH / 64, (n + 63) / 64);
        gemm_kernel<<<g, 256, 0, stream>>>(Abuf, W2, Hbuf, n, HH, HH);
        rowdots_kernel<<<wgrid, 256, 0, stream>>>(Hbuf, a2s, a2d, ssrc, sdst, n, HH);
        agg_kernel<4, true, false><<<wgrid, 256, 0, stream>>>(Hbuf, ssrc, sdst, off, es, b2, Abuf, n, HH);
    }
    // --- layer 4: A[N,256] @ W3 -> H[N,128], agg + feature softmax -> d_out ---
    {
        dim3 g(DOUT / 64, (n + 63) / 64);
        gemm_kernel<<<g, 256, 0, stream>>>(Abuf, W3, Hbuf, n, HH, DOUT);
        rowdots_kernel<<<wgrid, 256, 0, stream>>>(Hbuf, a3s, a3d, ssrc, sdst, n, DOUT);
        agg_kernel<2, false, true><<<wgrid, 256, 0, stream>>>(Hbuf, ssrc, sdst, off, es, b3, (float*)d_out, n, DOUT);
    }
}